// Round 1
// baseline (767.641 us; speedup 1.0000x reference)
//
#include <hip/hip_runtime.h>
#include <hip/hip_bf16.h>
#include <stdint.h>

#define N_NODES 100000
#define DIM     64
#define NRELS   16
#define NBASE   8
#define HDIM    128
#define NEDGE   3200000
#define KDIM    1024   /* NRELS*DIM */

typedef __attribute__((ext_vector_type(8))) short  short8;
typedef __attribute__((ext_vector_type(4))) float  f32x4;

/* ws layout (fast path):
   [0, 256KB)            : Veff in bf16, MFMA-B-fragment order
   [256KB, +204.8MB)     : supports bf16 [N][1024]                     */
#define VEFF_FRAG_BYTES (KDIM * HDIM * 2)
#define SUPPORTS_OFF    ((size_t)VEFF_FRAG_BYTES)
#define SUPPORTS_BYTES  ((size_t)N_NODES * KDIM * 2)
#define WS_FAST_NEED    (SUPPORTS_OFF + SUPPORTS_BYTES)

static __device__ __forceinline__ unsigned short f2bf(float x) {
    union { float f; unsigned u; } t; t.f = x;
    unsigned u = t.u;
    unsigned r = u + 0x7FFFu + ((u >> 16) & 1u);   /* RNE */
    return (unsigned short)(r >> 16);
}
static __device__ __forceinline__ unsigned pack2bf16(float a, float b) {
    return (unsigned)f2bf(a) | ((unsigned)f2bf(b) << 16);
}

/* ---- kernel 1: build Veff in MFMA B-fragment layout ----
   Veff[c][h] = sum_b W_comp[c&15, b] * W[b*64 + (c>>4), h]
   frag elem (kt, hb, lane, j) = B[k = kt*32 + (lane>>4)*8 + j][h = hb*16 + (lane&15)] */
__global__ __launch_bounds__(256) void build_veff_frag(
        const float* __restrict__ W, const float* __restrict__ Wc,
        __hip_bfloat16* __restrict__ veff) {
    int idx = blockIdx.x * 256 + threadIdx.x;   /* 131072 total */
    int c = idx >> 7;
    int h = idx & 127;
    int r_ = c & 15;
    int d_ = c >> 4;
    float acc = 0.f;
#pragma unroll
    for (int b = 0; b < NBASE; ++b)
        acc += Wc[r_ * NBASE + b] * W[(b * DIM + d_) * HDIM + h];
    int kt = c >> 5, ko = c & 31;
    int lane = ((ko >> 3) << 4) | (h & 15);
    int j = ko & 7;
    int hb = h >> 4;
    ((unsigned short*)veff)[(size_t)((kt * 8 + hb) * 64 + lane) * 8 + j] = f2bf(acc);
}

/* ---- kernel 2: edge scatter with pk bf16 atomics ---- */
__global__ __launch_bounds__(256) void scatter_edges(
        const float* __restrict__ vertex, const float* __restrict__ eval,
        const int* __restrict__ esrc, const int* __restrict__ edst,
        const int* __restrict__ erel, __hip_bfloat16* __restrict__ supports) {
    int tid = blockIdx.x * 256 + threadIdx.x;   /* E*16 threads exactly */
    int e = tid >> 4;
    int p = tid & 15;
    int src = esrc[e], dst = edst[e], rel = erel[e];
    float val = eval[e];
    float4 v = ((const float4*)vertex)[(size_t)src * 16 + p];
    unsigned lo = pack2bf16(v.x * val, v.y * val);
    unsigned hi = pack2bf16(v.z * val, v.w * val);
    __hip_bfloat16* base = supports + ((size_t)(dst * 16 + rel) * 64 + p * 4);
    asm volatile("global_atomic_pk_add_bf16 %0, %1, off" :: "v"(base),     "v"(lo) : "memory");
    asm volatile("global_atomic_pk_add_bf16 %0, %1, off" :: "v"(base + 2), "v"(hi) : "memory");
}

/* ---- kernel 3: [N,1024]bf16 @ Veff[1024,128]bf16 + bias -> out fp32 ----
   block: 128 rows x 128 cols, 4 waves (each 32 rows x 128 cols), K-step 128 */
__global__ __launch_bounds__(256) void gemm_out(
        const __hip_bfloat16* __restrict__ supports,
        const __hip_bfloat16* __restrict__ veff,
        const float* __restrict__ bias, float* __restrict__ out) {
    __shared__ __align__(16) unsigned char smem[32 * 1024]; /* A tile 128x128 bf16, XOR-swizzled */
    int t = threadIdx.x;
    int n0 = blockIdx.x * 128;
    int wave = t >> 6, lane = t & 63;
    int l15 = lane & 15, lhi = lane >> 4;

    f32x4 acc[2][8];
#pragma unroll
    for (int i = 0; i < 2; ++i)
#pragma unroll
        for (int j = 0; j < 8; ++j) acc[i][j] = (f32x4)0.f;

    int arow = t >> 1;           /* 0..127 */
    int ahalf = t & 1;
    int rowg = n0 + arow; if (rowg > N_NODES - 1) rowg = N_NODES - 1;
    const uint4* aglob = (const uint4*)((const char*)supports + (size_t)rowg * (KDIM * 2));

    for (int kk = 0; kk < 8; ++kk) {
        const uint4* gsrc = aglob + kk * 16 + ahalf * 8;
#pragma unroll
        for (int i = 0; i < 8; ++i) {
            uint4 q = gsrc[i];
            int boff = ahalf * 128 + i * 16;
            *(uint4*)(smem + arow * 256 + (boff ^ ((arow & 7) << 4))) = q;
        }
        __syncthreads();
#pragma unroll
        for (int kb = 0; kb < 4; ++kb) {
            int kt = kk * 4 + kb;
            short8 bfrag[8];
#pragma unroll
            for (int hb = 0; hb < 8; ++hb)
                bfrag[hb] = ((const short8*)veff)[(size_t)(kt * 8 + hb) * 64 + lane];
            short8 afrag[2];
#pragma unroll
            for (int rb = 0; rb < 2; ++rb) {
                int rr = wave * 32 + rb * 16 + l15;
                int bc = kb * 64 + lhi * 16;
                afrag[rb] = *(const short8*)(smem + rr * 256 + (bc ^ ((rr & 7) << 4)));
            }
#pragma unroll
            for (int rb = 0; rb < 2; ++rb)
#pragma unroll
                for (int hb = 0; hb < 8; ++hb)
                    acc[rb][hb] = __builtin_amdgcn_mfma_f32_16x16x32_bf16(
                        afrag[rb], bfrag[hb], acc[rb][hb], 0, 0, 0);
        }
        __syncthreads();
    }
#pragma unroll
    for (int hb = 0; hb < 8; ++hb) {
        int h = hb * 16 + l15;
        float bv = bias[h];
#pragma unroll
        for (int rb = 0; rb < 2; ++rb) {
            int nrow = n0 + wave * 32 + rb * 16 + lhi * 4;
#pragma unroll
            for (int j = 0; j < 4; ++j) {
                int n = nrow + j;
                if (n < N_NODES) out[(size_t)n * HDIM + h] = acc[rb][hb][j] + bv;
            }
        }
    }
}

/* ---------- slow fallback (only if ws too small) ---------- */
__global__ __launch_bounds__(256) void build_veff_plain(
        const float* __restrict__ W, const float* __restrict__ Wc,
        float* __restrict__ veff) {
    int idx = blockIdx.x * 256 + threadIdx.x;
    int c = idx >> 7, h = idx & 127;
    float acc = 0.f;
#pragma unroll
    for (int b = 0; b < NBASE; ++b)
        acc += Wc[(c & 15) * NBASE + b] * W[(b * DIM + (c >> 4)) * HDIM + h];
    veff[c * HDIM + h] = acc;
}
__global__ __launch_bounds__(256) void init_out_bias(
        const float* __restrict__ bias, float* __restrict__ out) {
    int idx = blockIdx.x * 256 + threadIdx.x;
    if (idx < N_NODES * HDIM) out[idx] = bias[idx & 127];
}
__global__ __launch_bounds__(128) void edge_slow(
        const float* __restrict__ vertex, const float* __restrict__ eval,
        const int* __restrict__ esrc, const int* __restrict__ edst,
        const int* __restrict__ erel, const float* __restrict__ veff,
        float* __restrict__ out) {
    int e = blockIdx.x;
    int h = threadIdx.x;
    __shared__ float vrow[DIM];
    int src = esrc[e], dst = edst[e], rel = erel[e];
    float val = eval[e];
    if (h < DIM) vrow[h] = vertex[(size_t)src * DIM + h];
    __syncthreads();
    float acc = 0.f;
#pragma unroll 8
    for (int d = 0; d < DIM; ++d)
        acc += vrow[d] * veff[(rel * DIM + d) * HDIM + h];
    atomicAdd(out + (size_t)dst * HDIM + h, val * acc);
}

extern "C" void kernel_launch(void* const* d_in, const int* in_sizes, int n_in,
                              void* d_out, int out_size, void* d_ws, size_t ws_size,
                              hipStream_t stream) {
    const float* vertex   = (const float*)d_in[0];
    const float* edge_val = (const float*)d_in[1];
    const float* W        = (const float*)d_in[2];
    const float* W_comp   = (const float*)d_in[3];
    const float* B        = (const float*)d_in[4];
    const int*   edge_src = (const int*)d_in[5];
    const int*   edge_dst = (const int*)d_in[6];
    const int*   edge_rel = (const int*)d_in[7];
    float* out = (float*)d_out;

    if (ws_size >= WS_FAST_NEED) {
        __hip_bfloat16* veff     = (__hip_bfloat16*)d_ws;
        __hip_bfloat16* supports = (__hip_bfloat16*)((char*)d_ws + SUPPORTS_OFF);
        build_veff_frag<<<KDIM * HDIM / 256, 256, 0, stream>>>(W, W_comp, veff);
        hipMemsetAsync(supports, 0, SUPPORTS_BYTES, stream);
        scatter_edges<<<NEDGE * 16 / 256, 256, 0, stream>>>(
            vertex, edge_val, edge_src, edge_dst, edge_rel, supports);
        gemm_out<<<(N_NODES + 127) / 128, 256, 0, stream>>>(supports, veff, B, out);
    } else {
        float* veff = (float*)d_ws;   /* 512 KB */
        build_veff_plain<<<KDIM * HDIM / 256, 256, 0, stream>>>(W, W_comp, veff);
        init_out_bias<<<(N_NODES * HDIM + 255) / 256, 256, 0, stream>>>(B, out);
        edge_slow<<<NEDGE, 128, 0, stream>>>(
            vertex, edge_val, edge_src, edge_dst, edge_rel, veff, out);
    }
}